// Round 5
// baseline (209.140 us; speedup 1.0000x reference)
//
#include <hip/hip_runtime.h>

typedef __bf16 bf16;
typedef bf16 bf16x4 __attribute__((ext_vector_type(4)));
typedef bf16 bf16x8 __attribute__((ext_vector_type(8)));
typedef float f32x4 __attribute__((ext_vector_type(4)));

#define NT 4   // tiles (of 4 points) per wave; 16 points/wave, 64/block

// LDS: W 64 rows x 200 bf16 (400B pitch) = 25600 B (block-shared, read-only after stage)
//      T 4 waves x 16 rows x 200 bf16   = 25600 B (wave-private)
// total 51200 B -> 3 blocks/CU. ONE __syncthreads (W stage); steady state barrier-free:
// T rows m=4q+i are wave-private (pad rows m%4==3 never written/stored), so the
// transpose round-trip is same-wave lgkmcnt only. J/X for tile t+1 prefetched into
// registers while tile t computes -> HBM latency overlapped, not just occupancy-hidden.

__global__ __launch_bounds__(256, 3)
void affine_linear_fused(const float* __restrict__ X, const float* __restrict__ J,
                         const float* __restrict__ A, const float* __restrict__ Bm,
                         const float* __restrict__ C, float* __restrict__ Y)
{
    __shared__ __attribute__((aligned(16))) bf16 Wl[64 * 200];
    __shared__ __attribute__((aligned(16))) bf16 Tl[4][16 * 200];

    const int tid  = threadIdx.x;
    const int wave = tid >> 6;
    const int lane = tid & 63;
    const int l16  = lane & 15;
    const int lq   = lane >> 4;                      // quad 0..3
    const long wp0 = (long)blockIdx.x * 64 + wave * 16;   // this wave's first point

    float jr[2][4][6], xr[2][4][3];                  // double-buffered prefetch regs
    auto issue_tile = [&](int t, int s) {
        #pragma unroll
        for (int q = 0; q < 4; ++q) {
            const float* jp = J + (wp0 + t*4 + q) * 384 + lane * 6;   // 8B-aligned
            float2 j01 = *(const float2*)(jp + 0);
            float2 j23 = *(const float2*)(jp + 2);
            float2 j45 = *(const float2*)(jp + 4);
            jr[s][q][0] = j01.x; jr[s][q][1] = j01.y;
            jr[s][q][2] = j23.x; jr[s][q][3] = j23.y;
            jr[s][q][4] = j45.x; jr[s][q][5] = j45.y;
            const float* xp = X + (wp0 + t*4 + q) * 192 + lane * 3;
            xr[s][q][0] = xp[0]; xr[s][q][1] = xp[1]; xr[s][q][2] = xp[2];
        }
    };

    issue_tile(0, 0);   // tile-0 loads in flight during W staging

    // ---- Stage W = [A|Bm|C] -> LDS bf16, row f, k = seg*64 + d ----
    #pragma unroll
    for (int it = 0; it < 4; ++it) {
        int idx = tid + it * 256;            // 0..1023
        int f = idx >> 4, d4 = (idx & 15) * 4;
        f32x4 va = *(const f32x4*)(A  + f*64 + d4);
        f32x4 vb = *(const f32x4*)(Bm + f*64 + d4);
        f32x4 vc = *(const f32x4*)(C  + f*64 + d4);
        bf16* row = Wl + f * 200;
        *(bf16x4*)(row +       d4) = bf16x4{(bf16)va[0],(bf16)va[1],(bf16)va[2],(bf16)va[3]};
        *(bf16x4*)(row +  64 + d4) = bf16x4{(bf16)vb[0],(bf16)vb[1],(bf16)vb[2],(bf16)vb[3]};
        *(bf16x4*)(row + 128 + d4) = bf16x4{(bf16)vc[0],(bf16)vc[1],(bf16)vc[2],(bf16)vc[3]};
    }
    __syncthreads();   // the ONLY barrier; W read-only afterwards

    bf16* Tw = Tl[wave];

    #pragma unroll
    for (int t = 0; t < NT; ++t) {
        const int s = t & 1;
        if (t + 1 < NT) issue_tile(t + 1, (t + 1) & 1);   // prefetch next tile

        // ---- Terms for 4 points; T rows m = 4q+i (rows m%4==3 pad) ----
        #pragma unroll
        for (int q = 0; q < 4; ++q) {
            float a1x = jr[s][q][0], a2x = jr[s][q][1];
            float a1y = jr[s][q][2], a2y = jr[s][q][3];
            float a1z = jr[s][q][4], a2z = jr[s][q][5];
            float xx = xr[s][q][0], xy = xr[s][q][1], xz = xr[s][q][2];

            float n1   = sqrtf(a1x*a1x + a1y*a1y + a1z*a1z);
            float inv1 = 1.0f / fmaxf(n1, 1e-12f);
            float b1x = a1x*inv1, b1y = a1y*inv1, b1z = a1z*inv1;
            float dot = b1x*a2x + b1y*a2y + b1z*a2z;
            float ux = a2x - dot*b1x, uy = a2y - dot*b1y, uz = a2z - dot*b1z;
            float n2   = sqrtf(ux*ux + uy*uy + uz*uz);
            float inv2 = 1.0f / fmaxf(n2, 1e-12f);
            float b2x = ux*inv2, b2y = uy*inv2, b2z = uz*inv2;
            float b3x = b1y*b2z - b1z*b2y;
            float b3y = b1z*b2x - b1x*b2z;
            float b3z = b1x*b2y - b1y*b2x;

            float rt0 = b1x*xx + b1y*xy + b1z*xz;
            float rt1 = b2x*xx + b2y*xy + b2z*xz;
            float rt2 = b3x*xx + b3y*xy + b3z*xz;

            float at0 = b1x*rt0 + b2x*rt1;
            float at1 = b1y*rt0 + b2y*rt1;
            float at2 = b1z*rt0 + b2z*rt1;
            float bt0 = b2x*rt0 - b1x*rt1;
            float bt1 = b2y*rt0 - b1y*rt1;
            float bt2 = b2z*rt0 - b1z*rt1;
            float ct0 = b3x*rt2, ct1 = b3y*rt2, ct2 = b3z*rt2;

            bf16* r0 = Tw + (4*q + 0) * 200;
            bf16* r1 = Tw + (4*q + 1) * 200;
            bf16* r2 = Tw + (4*q + 2) * 200;
            r0[lane] = (bf16)at0; r0[64+lane] = (bf16)bt0; r0[128+lane] = (bf16)ct0;
            r1[lane] = (bf16)at1; r1[64+lane] = (bf16)bt1; r1[128+lane] = (bf16)ct1;
            r2[lane] = (bf16)at2; r2[64+lane] = (bf16)bt2; r2[128+lane] = (bf16)ct2;
        }
        // same-wave LDS RAW: compiler lgkmcnt, no barrier

        // ---- A-frags from own T: A[m=l16][k = kk*32 + lq*8 + j] ----
        const bf16* arow = Tw + l16 * 200 + lq * 8;
        bf16x8 af[6];
        #pragma unroll
        for (int kk = 0; kk < 6; ++kk) af[kk] = *(const bf16x8*)(arow + kk * 32);

        // ---- 4 N-tiles x 6 K MFMAs; D row = lq*4+r = 4q+i -> point=lq, i=r ----
        float* yb = Y + (wp0 + t*4 + lq) * 192 + l16 * 3;
        #pragma unroll
        for (int nt = 0; nt < 4; ++nt) {
            const bf16* wr = Wl + (nt*16 + l16) * 200 + lq * 8;
            f32x4 acc = {0.f, 0.f, 0.f, 0.f};
            #pragma unroll
            for (int kk = 0; kk < 6; ++kk)
                acc = __builtin_amdgcn_mfma_f32_16x16x32_bf16(
                          af[kk], *(const bf16x8*)(wr + kk*32), acc, 0, 0, 0);
            yb[nt*48 + 0] = acc[0];    // f = nt*16+l16, i = 0..2 (acc[3] is pad row)
            yb[nt*48 + 1] = acc[1];
            yb[nt*48 + 2] = acc[2];
        }
    }
}

extern "C" void kernel_launch(void* const* d_in, const int* in_sizes, int n_in,
                              void* d_out, int out_size, void* d_ws, size_t ws_size,
                              hipStream_t stream) {
    const float* X  = (const float*)d_in[0];
    const float* J  = (const float*)d_in[1];
    const float* A  = (const float*)d_in[2];
    const float* Bm = (const float*)d_in[3];
    const float* C  = (const float*)d_in[4];
    float* Y = (float*)d_out;

    const int points = in_sizes[0] / (64 * 3);   // B*N = 65536
    const int blocks = points / 64;              // 1024 (64 points per block)
    affine_linear_fused<<<blocks, 256, 0, stream>>>(X, J, A, Bm, C, Y);
}